// Round 4
// baseline (562.614 us; speedup 1.0000x reference)
//
#include <hip/hip_runtime.h>
#include <hip/hip_bf16.h>
#include <stdint.h>

#define NQ 128
#define NLVL 5

typedef float  floatx4 __attribute__((ext_vector_type(4)));
typedef short  short8  __attribute__((ext_vector_type(8)));

__device__ __forceinline__ uint16_t f2bf(float f) {
    uint32_t u = __builtin_bit_cast(uint32_t, f);
    uint32_t r = u + 0x7FFFu + ((u >> 16) & 1u);   // RNE
    return (uint16_t)(r >> 16);
}
__device__ __forceinline__ uint32_t pk2bf(float a, float b) {
    return (uint32_t)f2bf(a) | ((uint32_t)f2bf(b) << 16);
}
__device__ __forceinline__ float bf_lo(uint32_t p) { return __builtin_bit_cast(float, p << 16); }
__device__ __forceinline__ float bf_hi(uint32_t p) { return __builtin_bit_cast(float, p & 0xFFFF0000u); }

// ---------------------------------------------------------------- configs ----
struct LvlCfg {
    const float* x;       // (N, C, HW)
    float*       part;    // partial G tiles: (((n*nch+ch)*nt+ti)*nt+tj)*R*R
    uint16_t*    smT;     // (NQ, C) bf16, K-contiguous
    const float* smN;     // (C, NQ) fp32, o-contiguous
    int C, HW, nt, R, nch, chunkH, ksteps;
    int gramBase, gramCnt, qformBase;
};
struct GramParams { LvlCfg l[NLVL]; };

// ---------------------------------------------------------------- softmax ----
struct SmParams {
    const float* w[NLVL];
    uint16_t*    smT[NLVL];
    float*       smN[NLVL];
    int          C[NLVL];
};

__global__ __launch_bounds__(64) void softmax_kernel(SmParams p) {
    int b   = blockIdx.x;      // 5*128 blocks
    int lvl = b >> 7;
    int o   = b & 127;
    int C   = p.C[lvl];
    const float* w = p.w[lvl];
    int lane = threadIdx.x;
    float ev[8];
    int nIter = C >> 6;
    float mx = -1e30f;
    for (int it = 0; it < nIter; ++it) {
        float z = 10.0f * w[(size_t)(it * 64 + lane) * NQ + o];
        ev[it] = z;
        mx = fmaxf(mx, z);
    }
    #pragma unroll
    for (int s = 32; s; s >>= 1) mx = fmaxf(mx, __shfl_xor(mx, s));
    float sum = 0.f;
    for (int it = 0; it < nIter; ++it) { ev[it] = expf(ev[it] - mx); sum += ev[it]; }
    #pragma unroll
    for (int s = 32; s; s >>= 1) sum += __shfl_xor(sum, s);
    float inv = 1.0f / sum;
    uint16_t* dstT = p.smT[lvl] + (size_t)o * C;
    float*    dstN = p.smN[lvl];
    for (int it = 0; it < nIter; ++it) {
        float v = ev[it] * inv;
        int c = it * 64 + lane;
        dstT[c] = f2bf(v);
        dstN[(size_t)c * NQ + o] = v;
    }
}

// --------------------------------------------------------------- w transpose -
struct TrCfg { const float* src; float* dst; int K, O, base; };
struct TrParams { TrCfg m[3]; };

__global__ __launch_bounds__(256) void wtrans_kernel(TrParams p) {
    __shared__ float tile[32][33];
    int bid = blockIdx.x;
    int mi = 0;
    #pragma unroll
    for (int i = 1; i < 3; ++i) if (bid >= p.m[i].base) mi = i;
    TrCfg c = p.m[mi];
    int rel = bid - c.base;
    int ox = c.O >> 5;
    int ty = rel / ox, tx = rel - ty * ox;
    int k0 = ty * 32, o0 = tx * 32;
    int t = threadIdx.x;
    int lr = t >> 5;        // 0..7
    int lc = t & 31;
    #pragma unroll
    for (int i = 0; i < 4; ++i)
        tile[lr + 8 * i][lc] = c.src[(size_t)(k0 + lr + 8 * i) * c.O + o0 + lc];
    __syncthreads();
    #pragma unroll
    for (int i = 0; i < 4; ++i)
        c.dst[(size_t)(o0 + lr + 8 * i) * c.K + k0 + lc] = tile[lc][lr + 8 * i];
}

// ------------------------------------------------------------------- gram ----
// G[c,c'] = sum_h x[c,h] x[c',h]. Deep barrier windows:
//   R==64  (lvl0): BK=128, At[64][136]
//   R==128       : BK=64,  At/Bt[128][72]
__global__ __launch_bounds__(256) void gram_kernel(GramParams p) {
    __shared__ __align__(16) short At[9216];
    __shared__ __align__(16) short Bt[9216];

    int bid = blockIdx.x;
    int lvl = 0;
    #pragma unroll
    for (int i = 0; i < NLVL; ++i)
        if (bid >= p.l[i].gramBase && bid < p.l[i].gramBase + p.l[i].gramCnt) lvl = i;
    LvlCfg cf = p.l[lvl];
    int rel  = bid - cf.gramBase;
    int ntt  = cf.nt * cf.nt;
    int pern = cf.nch * ntt;
    int n  = rel / pern;        int r2 = rel - n * pern;
    int ch = r2 / ntt;          int r3 = r2 - ch * ntt;
    int ti = r3 / cf.nt;        int tj = r3 - ti * cf.nt;
    bool diag = (ti == tj);
    int HW = cf.HW;

    const float* xa = cf.x + ((size_t)n * cf.C + ti * 128) * HW + (size_t)ch * cf.chunkH;
    const float* xb = cf.x + ((size_t)n * cf.C + tj * 128) * HW + (size_t)ch * cf.chunkH;

    int t = threadIdx.x, wave = t >> 6, lane = t & 63;
    int m = lane & 15, kg = lane >> 4;

    floatx4 acc[2][8];
    #pragma unroll
    for (int i = 0; i < 2; ++i)
        #pragma unroll
        for (int j = 0; j < 8; ++j) acc[i][j] = (floatx4){0.f, 0.f, 0.f, 0.f};

    if (cf.R == 64) {
        // ---- lvl0 path: 64x64 diag tile, BK=128
        int row0 = t >> 5, c4 = t & 31;
        const float* g0 = xa + (size_t)row0 * HW + c4 * 4;
        short* lp = &At[row0 * 136 + c4 * 4];
        for (int st = 0; st < cf.ksteps; ++st) {
            const float* g = g0 + st * 128;
            #pragma unroll
            for (int half = 0; half < 2; ++half) {
                floatx4 v[4];
                #pragma unroll
                for (int i = 0; i < 4; ++i)
                    v[i] = *(const floatx4*)(g + (size_t)(half * 4 + i) * 8 * HW);
                #pragma unroll
                for (int i = 0; i < 4; ++i) {
                    uint2 u; u.x = pk2bf(v[i].x, v[i].y); u.y = pk2bf(v[i].z, v[i].w);
                    *(uint2*)(lp + (half * 4 + i) * 8 * 136) = u;
                }
            }
            __syncthreads();
            #pragma unroll
            for (int sub = 0; sub < 4; ++sub) {
                int ko = sub * 32 + kg * 8;
                short8 a8 = *(const short8*)&At[(wave * 16 + m) * 136 + ko];
                #pragma unroll
                for (int ot = 0; ot < 4; ++ot) {
                    short8 b8 = *(const short8*)&At[(ot * 16 + m) * 136 + ko];
                    acc[0][ot] = __builtin_amdgcn_mfma_f32_16x16x32_bf16(a8, b8, acc[0][ot], 0, 0, 0);
                }
            }
            __syncthreads();
        }
    } else {
        // ---- 128x128 tiles, BK=64
        int row0 = t >> 4, c4 = t & 15;
        size_t goff = (size_t)row0 * HW + c4 * 4;
        int loff = row0 * 72 + c4 * 4;
        for (int st = 0; st < cf.ksteps; ++st) {
            const float* ga = xa + goff + st * 64;
            #pragma unroll
            for (int half = 0; half < 2; ++half) {
                floatx4 v[4];
                #pragma unroll
                for (int i = 0; i < 4; ++i)
                    v[i] = *(const floatx4*)(ga + (size_t)(half * 4 + i) * 16 * HW);
                #pragma unroll
                for (int i = 0; i < 4; ++i) {
                    uint2 u; u.x = pk2bf(v[i].x, v[i].y); u.y = pk2bf(v[i].z, v[i].w);
                    *(uint2*)&At[loff + (half * 4 + i) * 16 * 72] = u;
                }
            }
            if (!diag) {
                const float* gb = xb + goff + st * 64;
                #pragma unroll
                for (int half = 0; half < 2; ++half) {
                    floatx4 v[4];
                    #pragma unroll
                    for (int i = 0; i < 4; ++i)
                        v[i] = *(const floatx4*)(gb + (size_t)(half * 4 + i) * 16 * HW);
                    #pragma unroll
                    for (int i = 0; i < 4; ++i) {
                        uint2 u; u.x = pk2bf(v[i].x, v[i].y); u.y = pk2bf(v[i].z, v[i].w);
                        *(uint2*)&Bt[loff + (half * 4 + i) * 16 * 72] = u;
                    }
                }
            }
            __syncthreads();
            const short* Bs = diag ? At : Bt;
            #pragma unroll
            for (int sub = 0; sub < 2; ++sub) {
                int ko = sub * 32 + kg * 8;
                short8 a8[2];
                #pragma unroll
                for (int mt = 0; mt < 2; ++mt)
                    a8[mt] = *(const short8*)&At[((wave * 2 + mt) * 16 + m) * 72 + ko];
                #pragma unroll
                for (int ot = 0; ot < 8; ++ot) {
                    short8 b8 = *(const short8*)&Bs[(ot * 16 + m) * 72 + ko];
                    #pragma unroll
                    for (int mt = 0; mt < 2; ++mt)
                        acc[mt][ot] = __builtin_amdgcn_mfma_f32_16x16x32_bf16(a8[mt], b8, acc[mt][ot], 0, 0, 0);
                }
            }
            __syncthreads();
        }
    }

    // ---- store partial tile
    int R = cf.R;
    int mtCnt = R >> 6, otCnt = R >> 4, mtBase = wave * mtCnt;
    size_t tileElems = (size_t)R * R;
    float* pd = cf.part + (((size_t)(n * cf.nch + ch) * cf.nt + ti) * cf.nt + tj) * tileElems;
    for (int mt = 0; mt < mtCnt; ++mt)
        for (int ot = 0; ot < otCnt; ++ot)
            #pragma unroll
            for (int r = 0; r < 4; ++r) {
                int row = (mtBase + mt) * 16 + kg * 4 + r;
                int col = ot * 16 + m;
                pd[(size_t)row * R + col] = acc[mt][ot][r];
            }
}

// ------------------------------------------------------------------ reduce ---
// Sum partial chunks into chunk-0 slot (levels with nch>1), massively parallel.
struct RedLvl { float* part; int nch; int shift; int base; };
struct RedParams { RedLvl r[3]; };

__global__ __launch_bounds__(256) void reduce_kernel(RedParams p) {
    int bid = blockIdx.x;
    int li = 0;
    #pragma unroll
    for (int i = 1; i < 3; ++i) if (bid >= p.r[i].base) li = i;
    RedLvl c = p.r[li];
    int rel = bid - c.base;
    int idx = rel * 256 + (int)threadIdx.x;
    int n   = idx >> c.shift;
    int i4  = idx & ((1 << c.shift) - 1);
    floatx4* p4 = (floatx4*)c.part;
    size_t b = ((size_t)n * c.nch) << c.shift;
    floatx4 s0 = {0,0,0,0}, s1 = {0,0,0,0}, s2 = {0,0,0,0}, s3 = {0,0,0,0};
    int ch = 0;
    for (; ch + 4 <= c.nch; ch += 4) {
        s0 += p4[b + ((size_t)ch       << c.shift) + i4];
        s1 += p4[b + ((size_t)(ch + 1) << c.shift) + i4];
        s2 += p4[b + ((size_t)(ch + 2) << c.shift) + i4];
        s3 += p4[b + ((size_t)(ch + 3) << c.shift) + i4];
    }
    for (; ch < c.nch; ++ch) s0 += p4[b + ((size_t)ch << c.shift) + i4];
    p4[b + i4] = (s0 + s1) + (s2 + s3);
}

// ------------------------------------------------------------------ qform ----
// T = G @ smT (G from reduced chunk-0, split hi/lo bf16); quad[o] += sm.T
__global__ __launch_bounds__(256) void qform_kernel(GramParams p, float* quad) {
    __shared__ __align__(16) short Ahi[128 * 40];
    __shared__ __align__(16) short Alo[128 * 40];
    __shared__ __align__(16) short Bs [128 * 40];

    int bid = blockIdx.x;
    int lvl = 0;
    #pragma unroll
    for (int i = 1; i < NLVL; ++i) if (bid >= p.l[i].qformBase) lvl = i;
    LvlCfg cf = p.l[lvl];
    int rel = bid - cf.qformBase;
    int n  = rel / cf.nt;
    int mb = rel - n * cf.nt;
    int R = cf.R;

    int t = threadIdx.x, wave = t >> 6, lane = t & 63;
    int m = lane & 15, kg = lane >> 4;
    int aIt    = R >> 5;
    int mtCnt  = R >> 6;
    int mtBase = wave * mtCnt;

    floatx4 acc[2][8];
    #pragma unroll
    for (int i = 0; i < 2; ++i)
        #pragma unroll
        for (int j = 0; j < 8; ++j) acc[i][j] = (floatx4){0.f, 0.f, 0.f, 0.f};

    size_t tileElems = (size_t)R * R;

    for (int ks = 0; ks < cf.C; ks += 32) {
        int tjk = ks >> 7;
        int kin = ks & 127;
        // ---- A staging: read reduced G tile (chunk 0), split hi/lo bf16
        #pragma unroll
        for (int i = 0; i < 4; ++i) if (i < aIt) {
            int row = (t >> 3) + 32 * i;
            int k4  = (t & 7) * 4;
            const float* src = cf.part
                + (((size_t)n * cf.nch * cf.nt + mb) * cf.nt + tjk) * tileElems
                + (size_t)row * R + kin + k4;
            floatx4 s = *(const floatx4*)src;
            uint32_t h0 = pk2bf(s.x, s.y), h1 = pk2bf(s.z, s.w);
            floatx4 resid;
            resid.x = s.x - bf_lo(h0); resid.y = s.y - bf_hi(h0);
            resid.z = s.z - bf_lo(h1); resid.w = s.w - bf_hi(h1);
            uint2 uh; uh.x = h0; uh.y = h1;
            uint2 ul; ul.x = pk2bf(resid.x, resid.y); ul.y = pk2bf(resid.z, resid.w);
            *(uint2*)&Ahi[row * 40 + k4] = uh;
            *(uint2*)&Alo[row * 40 + k4] = ul;
        }
        // ---- B staging: smT[o][ks..ks+32): 128 rows x 4 uint4 = 512 slots
        #pragma unroll
        for (int it = 0; it < 2; ++it) {
            int idx  = it * 256 + t;
            int o    = idx >> 2;
            int part = idx & 3;
            uint4 v = *(const uint4*)(cf.smT + (size_t)o * cf.C + ks + part * 8);
            *(uint4*)&Bs[o * 40 + part * 8] = v;
        }
        __syncthreads();

        short8 ah[2], al[2];
        #pragma unroll
        for (int mt = 0; mt < 2; ++mt) if (mt < mtCnt) {
            ah[mt] = *(const short8*)&Ahi[((mtBase + mt) * 16 + m) * 40 + kg * 8];
            al[mt] = *(const short8*)&Alo[((mtBase + mt) * 16 + m) * 40 + kg * 8];
        }
        #pragma unroll
        for (int ot = 0; ot < 8; ++ot) {
            short8 b8 = *(const short8*)&Bs[(ot * 16 + m) * 40 + kg * 8];
            #pragma unroll
            for (int mt = 0; mt < 2; ++mt) if (mt < mtCnt) {
                acc[mt][ot] = __builtin_amdgcn_mfma_f32_16x16x32_bf16(ah[mt], b8, acc[mt][ot], 0, 0, 0);
                acc[mt][ot] = __builtin_amdgcn_mfma_f32_16x16x32_bf16(al[mt], b8, acc[mt][ot], 0, 0, 0);
            }
        }
        __syncthreads();
    }

    // ---- epilogue: quad[o] += sum_c sm[c,o] * T[c,o]
    const float* smN = cf.smN;
    float* qb = quad + (size_t)(lvl * 8 + n) * NQ;
    #pragma unroll
    for (int ot = 0; ot < 8; ++ot) {
        float s = 0.f;
        #pragma unroll
        for (int mt = 0; mt < 2; ++mt) if (mt < mtCnt)
            #pragma unroll
            for (int r = 0; r < 4; ++r) {
                int c = mb * 128 + (mtBase + mt) * 16 + kg * 4 + r;
                int o = ot * 16 + m;
                s = fmaf(acc[mt][ot][r], smN[(size_t)c * NQ + o], s);
            }
        s += __shfl_xor(s, 16);
        s += __shfl_xor(s, 32);
        if (lane < 16) atomicAdd(qb + ot * 16 + lane, s);
    }
}

// ------------------------------------------------------------------- head ----
__device__ __forceinline__ float block_sum512(float v, float* red8, int t) {
    #pragma unroll
    for (int s = 32; s; s >>= 1) v += __shfl_xor(v, s);
    __syncthreads();
    if ((t & 63) == 0) red8[t >> 6] = v;
    __syncthreads();
    float tot = 0.f;
    #pragma unroll
    for (int i = 0; i < 8; ++i) tot += red8[i];
    return tot;
}

__global__ __launch_bounds__(512) void head_kernel(
    const float* __restrict__ quad,
    const float* __restrict__ wt1, const float* __restrict__ fc1_b,
    const float* __restrict__ wt2, const float* __restrict__ fc2_b,
    const float* __restrict__ wt3, const float* __restrict__ fc3_b,
    float* __restrict__ out) {
    __shared__ float feat[640];
    __shared__ float hbuf[512];
    __shared__ float red8[8];
    __shared__ float stats[10];
    int n = blockIdx.x;
    int t = threadIdx.x;

    for (int idx = t; idx < 640; idx += 512) {
        int lvl = idx >> 7, o = idx & 127;
        feat[idx] = quad[(size_t)(lvl * 8 + n) * NQ + o];
    }
    __syncthreads();
    if (t < 5) {
        float s = 0.f;
        for (int i = 0; i < 128; ++i) s += feat[t * 128 + i];
        float mean = s * (1.f / 128.f);
        float v = 0.f;
        for (int i = 0; i < 128; ++i) { float d = feat[t * 128 + i] - mean; v += d * d; }
        stats[t]     = mean;
        stats[5 + t] = sqrtf(v * (1.f / 127.f)) + 1e-8f;
    }
    __syncthreads();
    for (int idx = t; idx < 640; idx += 512) {
        int lvl = idx >> 7;
        feat[idx] = (feat[idx] - stats[lvl]) / stats[5 + lvl];
    }
    __syncthreads();

    float acc = fc1_b[t];
    {
        const float* wr = wt1 + (size_t)t * 640;
        #pragma unroll 4
        for (int k = 0; k < 640; k += 4) {
            floatx4 wv = *(const floatx4*)(wr + k);
            floatx4 fv = *(const floatx4*)&feat[k];
            acc = fmaf(wv.x, fv.x, acc); acc = fmaf(wv.y, fv.y, acc);
            acc = fmaf(wv.z, fv.z, acc); acc = fmaf(wv.w, fv.w, acc);
        }
    }
    float mean = block_sum512(acc, red8, t) * (1.f / 512.f);
    float d    = acc - mean;
    float var  = block_sum512(d * d, red8, t) * (1.f / 511.f);
    float nv   = d / (sqrtf(var) + 1e-8f);
    __syncthreads();
    hbuf[t] = nv > 0.f ? nv : 0.01f * nv;
    __syncthreads();

    float acc2 = fc2_b[t];
    {
        const float* wr = wt2 + (size_t)t * 512;
        #pragma unroll 4
        for (int k = 0; k < 512; k += 4) {
            floatx4 wv = *(const floatx4*)(wr + k);
            floatx4 fv = *(const floatx4*)&hbuf[k];
            acc2 = fmaf(wv.x, fv.x, acc2); acc2 = fmaf(wv.y, fv.y, acc2);
            acc2 = fmaf(wv.z, fv.z, acc2); acc2 = fmaf(wv.w, fv.w, acc2);
        }
    }
    mean = block_sum512(acc2, red8, t) * (1.f / 512.f);
    d    = acc2 - mean;
    var  = block_sum512(d * d, red8, t) * (1.f / 511.f);
    nv   = d / (sqrtf(var) + 1e-8f);
    __syncthreads();
    hbuf[t] = nv > 0.f ? nv : 0.01f * nv;
    __syncthreads();

    if (t < 128) {
        float acc3 = fc3_b[t];
        const float* wr = wt3 + (size_t)t * 512;
        #pragma unroll 4
        for (int k = 0; k < 512; k += 4) {
            floatx4 wv = *(const floatx4*)(wr + k);
            floatx4 fv = *(const floatx4*)&hbuf[k];
            acc3 = fmaf(wv.x, fv.x, acc3); acc3 = fmaf(wv.y, fv.y, acc3);
            acc3 = fmaf(wv.z, fv.z, acc3); acc3 = fmaf(wv.w, fv.w, acc3);
        }
        out[(size_t)n * NQ + t] = acc3;
    }
}

// ----------------------------------------------------------------- launch ----
extern "C" void kernel_launch(void* const* d_in, const int* in_sizes, int n_in,
                              void* d_out, int out_size, void* d_ws, size_t ws_size,
                              hipStream_t stream) {
    static const int Cs  [NLVL] = {64, 128, 256, 512, 512};
    static const int HWs [NLVL] = {65536, 16384, 4096, 1024, 256};
    static const int NTs [NLVL] = {1, 1, 2, 4, 4};
    static const int Rs  [NLVL] = {64, 128, 128, 128, 128};
    static const int NCHs[NLVL] = {64, 16, 4, 1, 1};
    // launch order: big blocks first, sea of small lvl0 blocks last
    static const int ORDER[NLVL] = {2, 3, 1, 4, 0};

    const float* x[NLVL];
    const float* w[NLVL];
    for (int i = 0; i < NLVL; ++i) {
        x[i] = (const float*)d_in[2 * i];
        w[i] = (const float*)d_in[2 * i + 1];
    }
    const float* fc1_w = (const float*)d_in[10];
    const float* fc1_b = (const float*)d_in[11];
    const float* fc2_w = (const float*)d_in[12];
    const float* fc2_b = (const float*)d_in[13];
    const float* fc3_w = (const float*)d_in[14];
    const float* fc3_b = (const float*)d_in[15];

    // ---- workspace layout (~40.1 MB)
    char* ws = (char*)d_ws;
    size_t off = 0;
    float* part[NLVL];
    for (int l = 0; l < NLVL; ++l) {
        part[l] = (float*)(ws + off);
        off += (size_t)8 * NCHs[l] * NTs[l] * NTs[l] * Rs[l] * Rs[l] * sizeof(float);
    }
    uint16_t* smT[NLVL];
    for (int l = 0; l < NLVL; ++l) { smT[l] = (uint16_t*)(ws + off); off += (size_t)Cs[l] * NQ * sizeof(uint16_t); }
    off = (off + 15) & ~(size_t)15;
    float* smN[NLVL];
    for (int l = 0; l < NLVL; ++l) { smN[l] = (float*)(ws + off); off += (size_t)Cs[l] * NQ * sizeof(float); }
    float* wt1 = (float*)(ws + off); off += (size_t)512 * 640 * sizeof(float);
    float* wt2 = (float*)(ws + off); off += (size_t)512 * 512 * sizeof(float);
    float* wt3 = (float*)(ws + off); off += (size_t)128 * 512 * sizeof(float);
    float* quad = (float*)(ws + off); off += (size_t)NLVL * 8 * NQ * sizeof(float);
    (void)ws_size;

    // ---- params
    SmParams sp;
    for (int l = 0; l < NLVL; ++l) { sp.w[l] = w[l]; sp.smT[l] = smT[l]; sp.smN[l] = smN[l]; sp.C[l] = Cs[l]; }

    GramParams gp;
    int qBase = 0;
    for (int l = 0; l < NLVL; ++l) {
        LvlCfg& c = gp.l[l];
        c.x = x[l]; c.part = part[l]; c.smT = smT[l]; c.smN = smN[l];
        c.C = Cs[l]; c.HW = HWs[l]; c.nt = NTs[l]; c.R = Rs[l];
        c.nch = NCHs[l]; c.chunkH = HWs[l] / NCHs[l];
        c.ksteps = c.chunkH / (l == 0 ? 128 : 64);
        c.gramCnt = 8 * c.nch * c.nt * c.nt;
        c.qformBase = qBase; qBase += 8 * c.nt;
    }
    int gBase = 0;
    for (int i = 0; i < NLVL; ++i) {
        LvlCfg& c = gp.l[ORDER[i]];
        c.gramBase = gBase;
        gBase += c.gramCnt;       // total 1024
    }

    RedParams rp;
    rp.r[0] = {part[0], NCHs[0], 10, 0};     // 8*4096/4/256  = 32 blocks
    rp.r[1] = {part[1], NCHs[1], 12, 32};    // 8*16384/4/256 = 128 blocks
    rp.r[2] = {part[2], NCHs[2], 14, 160};   // 8*65536/4/256 = 512 blocks
    int rBlocks = 672;

    TrParams tp;
    tp.m[0] = {fc1_w, wt1, 640, 512, 0};
    tp.m[1] = {fc2_w, wt2, 512, 512, 320};
    tp.m[2] = {fc3_w, wt3, 512, 128, 576};

    // ---- launches
    softmax_kernel<<<NLVL * NQ, 64, 0, stream>>>(sp);
    wtrans_kernel<<<640, 256, 0, stream>>>(tp);
    hipMemsetAsync(quad, 0, (size_t)NLVL * 8 * NQ * sizeof(float), stream);
    gram_kernel<<<gBase, 256, 0, stream>>>(gp);            // 1024 blocks
    reduce_kernel<<<rBlocks, 256, 0, stream>>>(rp);
    qform_kernel<<<qBase, 256, 0, stream>>>(gp, quad);     // 96 blocks
    head_kernel<<<8, 512, 0, stream>>>(quad, wt1, fc1_b, wt2, fc2_b, wt3, fc3_b,
                                       (float*)d_out);
}

// Round 5
// 487.744 us; speedup vs baseline: 1.1535x; 1.1535x over previous
//
#include <hip/hip_runtime.h>
#include <hip/hip_bf16.h>
#include <stdint.h>

#define NQ 128
#define NLVL 5

typedef float  floatx4 __attribute__((ext_vector_type(4)));
typedef short  short8  __attribute__((ext_vector_type(8)));

__device__ __forceinline__ uint16_t f2bf(float f) {
    uint32_t u = __builtin_bit_cast(uint32_t, f);
    uint32_t r = u + 0x7FFFu + ((u >> 16) & 1u);   // RNE
    return (uint16_t)(r >> 16);
}
__device__ __forceinline__ uint32_t pk2bf(float a, float b) {
    return (uint32_t)f2bf(a) | ((uint32_t)f2bf(b) << 16);
}
__device__ __forceinline__ float bf_lo(uint32_t p) { return __builtin_bit_cast(float, p << 16); }
__device__ __forceinline__ float bf_hi(uint32_t p) { return __builtin_bit_cast(float, p & 0xFFFF0000u); }

// ---------------------------------------------------------------- configs ----
struct LvlCfg {
    const float* x;       // (N, C, HW)
    float*       part;    // partial G tiles: (((n*nch+ch)*nt+ti)*nt+tj)*R*R
    uint16_t*    smT;     // (NQ, C) bf16, K-contiguous
    const float* smN;     // (C, NQ) fp32, o-contiguous
    int C, HW, nt, R, nch, chunkH, ksteps;
    int gramBase, gramCnt, qformBase;
};
struct GramParams { LvlCfg l[NLVL]; };

// ---------------------------------------------------------------- softmax ----
struct SmParams {
    const float* w[NLVL];
    uint16_t*    smT[NLVL];
    float*       smN[NLVL];
    int          C[NLVL];
};

__global__ __launch_bounds__(64) void softmax_kernel(SmParams p) {
    int b   = blockIdx.x;      // 5*128 blocks
    int lvl = b >> 7;
    int o   = b & 127;
    int C   = p.C[lvl];
    const float* w = p.w[lvl];
    int lane = threadIdx.x;
    float ev[8];
    int nIter = C >> 6;
    float mx = -1e30f;
    for (int it = 0; it < nIter; ++it) {
        float z = 10.0f * w[(size_t)(it * 64 + lane) * NQ + o];
        ev[it] = z;
        mx = fmaxf(mx, z);
    }
    #pragma unroll
    for (int s = 32; s; s >>= 1) mx = fmaxf(mx, __shfl_xor(mx, s));
    float sum = 0.f;
    for (int it = 0; it < nIter; ++it) { ev[it] = expf(ev[it] - mx); sum += ev[it]; }
    #pragma unroll
    for (int s = 32; s; s >>= 1) sum += __shfl_xor(sum, s);
    float inv = 1.0f / sum;
    uint16_t* dstT = p.smT[lvl] + (size_t)o * C;
    float*    dstN = p.smN[lvl];
    for (int it = 0; it < nIter; ++it) {
        float v = ev[it] * inv;
        int c = it * 64 + lane;
        dstT[c] = f2bf(v);
        dstN[(size_t)c * NQ + o] = v;
    }
}

// --------------------------------------------------------------- w transpose -
struct TrCfg { const float* src; float* dst; int K, O, base; };
struct TrParams { TrCfg m[3]; };

__global__ __launch_bounds__(256) void wtrans_kernel(TrParams p) {
    __shared__ float tile[32][33];
    int bid = blockIdx.x;
    int mi = 0;
    #pragma unroll
    for (int i = 1; i < 3; ++i) if (bid >= p.m[i].base) mi = i;
    TrCfg c = p.m[mi];
    int rel = bid - c.base;
    int ox = c.O >> 5;
    int ty = rel / ox, tx = rel - ty * ox;
    int k0 = ty * 32, o0 = tx * 32;
    int t = threadIdx.x;
    int lr = t >> 5;        // 0..7
    int lc = t & 31;
    #pragma unroll
    for (int i = 0; i < 4; ++i)
        tile[lr + 8 * i][lc] = c.src[(size_t)(k0 + lr + 8 * i) * c.O + o0 + lc];
    __syncthreads();
    #pragma unroll
    for (int i = 0; i < 4; ++i)
        c.dst[(size_t)(o0 + lr + 8 * i) * c.K + k0 + lc] = tile[lc][lr + 8 * i];
}

// ------------------------------------------------------------------- gram ----
// G[c,c'] = sum_h x[c,h] x[c',h]. Deep barrier windows:
//   R==64  (lvl0): BK=128, At[64][136]
//   R==128       : BK=64,  At/Bt[128][72]
// NOTE: accumulators are declared INSIDE each branch and only ever indexed
// with compile-time constants — dynamic indexing forces a scratch spill
// (R4: WRITE_SIZE 577 MB, +550 MB HBM traffic).
__global__ __launch_bounds__(256) void gram_kernel(GramParams p) {
    __shared__ __align__(16) short At[9216];
    __shared__ __align__(16) short Bt[9216];

    int bid = blockIdx.x;
    int lvl = 0;
    #pragma unroll
    for (int i = 0; i < NLVL; ++i)
        if (bid >= p.l[i].gramBase && bid < p.l[i].gramBase + p.l[i].gramCnt) lvl = i;
    LvlCfg cf = p.l[lvl];
    int rel  = bid - cf.gramBase;
    int ntt  = cf.nt * cf.nt;
    int pern = cf.nch * ntt;
    int n  = rel / pern;        int r2 = rel - n * pern;
    int ch = r2 / ntt;          int r3 = r2 - ch * ntt;
    int ti = r3 / cf.nt;        int tj = r3 - ti * cf.nt;
    bool diag = (ti == tj);
    int HW = cf.HW;

    const float* xa = cf.x + ((size_t)n * cf.C + ti * 128) * HW + (size_t)ch * cf.chunkH;
    const float* xb = cf.x + ((size_t)n * cf.C + tj * 128) * HW + (size_t)ch * cf.chunkH;

    int t = threadIdx.x, wave = t >> 6, lane = t & 63;
    int m = lane & 15, kg = lane >> 4;

    if (cf.R == 64) {
        // ---- lvl0 path: 64x64 diag tile, BK=128
        floatx4 acc0, acc1, acc2, acc3;
        acc0 = acc1 = acc2 = acc3 = (floatx4){0.f, 0.f, 0.f, 0.f};
        int row0 = t >> 5, c4 = t & 31;
        const float* g0 = xa + (size_t)row0 * HW + c4 * 4;
        short* lp = &At[row0 * 136 + c4 * 4];
        for (int st = 0; st < cf.ksteps; ++st) {
            const float* g = g0 + st * 128;
            #pragma unroll
            for (int half = 0; half < 2; ++half) {
                floatx4 v[4];
                #pragma unroll
                for (int i = 0; i < 4; ++i)
                    v[i] = *(const floatx4*)(g + (size_t)(half * 4 + i) * 8 * HW);
                #pragma unroll
                for (int i = 0; i < 4; ++i) {
                    uint2 u; u.x = pk2bf(v[i].x, v[i].y); u.y = pk2bf(v[i].z, v[i].w);
                    *(uint2*)(lp + (half * 4 + i) * 8 * 136) = u;
                }
            }
            __syncthreads();
            #pragma unroll
            for (int sub = 0; sub < 4; ++sub) {
                int ko = sub * 32 + kg * 8;
                short8 a8 = *(const short8*)&At[(wave * 16 + m) * 136 + ko];
                short8 b0 = *(const short8*)&At[(0 * 16 + m) * 136 + ko];
                short8 b1 = *(const short8*)&At[(1 * 16 + m) * 136 + ko];
                short8 b2 = *(const short8*)&At[(2 * 16 + m) * 136 + ko];
                short8 b3 = *(const short8*)&At[(3 * 16 + m) * 136 + ko];
                acc0 = __builtin_amdgcn_mfma_f32_16x16x32_bf16(a8, b0, acc0, 0, 0, 0);
                acc1 = __builtin_amdgcn_mfma_f32_16x16x32_bf16(a8, b1, acc1, 0, 0, 0);
                acc2 = __builtin_amdgcn_mfma_f32_16x16x32_bf16(a8, b2, acc2, 0, 0, 0);
                acc3 = __builtin_amdgcn_mfma_f32_16x16x32_bf16(a8, b3, acc3, 0, 0, 0);
            }
            __syncthreads();
        }
        float* pd = cf.part + ((size_t)(n * cf.nch + ch)) * 4096;
        int rowb = wave * 16 + kg * 4;
        #pragma unroll
        for (int r = 0; r < 4; ++r) {
            pd[(size_t)(rowb + r) * 64 + 0 * 16 + m] = acc0[r];
            pd[(size_t)(rowb + r) * 64 + 1 * 16 + m] = acc1[r];
            pd[(size_t)(rowb + r) * 64 + 2 * 16 + m] = acc2[r];
            pd[(size_t)(rowb + r) * 64 + 3 * 16 + m] = acc3[r];
        }
    } else {
        // ---- 128x128 tiles, BK=64
        floatx4 acc[2][8];
        #pragma unroll
        for (int i = 0; i < 2; ++i)
            #pragma unroll
            for (int j = 0; j < 8; ++j) acc[i][j] = (floatx4){0.f, 0.f, 0.f, 0.f};
        int row0 = t >> 4, c4 = t & 15;
        size_t goff = (size_t)row0 * HW + c4 * 4;
        int loff = row0 * 72 + c4 * 4;
        for (int st = 0; st < cf.ksteps; ++st) {
            const float* ga = xa + goff + st * 64;
            #pragma unroll
            for (int half = 0; half < 2; ++half) {
                floatx4 v[4];
                #pragma unroll
                for (int i = 0; i < 4; ++i)
                    v[i] = *(const floatx4*)(ga + (size_t)(half * 4 + i) * 16 * HW);
                #pragma unroll
                for (int i = 0; i < 4; ++i) {
                    uint2 u; u.x = pk2bf(v[i].x, v[i].y); u.y = pk2bf(v[i].z, v[i].w);
                    *(uint2*)&At[loff + (half * 4 + i) * 16 * 72] = u;
                }
            }
            if (!diag) {
                const float* gb = xb + goff + st * 64;
                #pragma unroll
                for (int half = 0; half < 2; ++half) {
                    floatx4 v[4];
                    #pragma unroll
                    for (int i = 0; i < 4; ++i)
                        v[i] = *(const floatx4*)(gb + (size_t)(half * 4 + i) * 16 * HW);
                    #pragma unroll
                    for (int i = 0; i < 4; ++i) {
                        uint2 u; u.x = pk2bf(v[i].x, v[i].y); u.y = pk2bf(v[i].z, v[i].w);
                        *(uint2*)&Bt[loff + (half * 4 + i) * 16 * 72] = u;
                    }
                }
            }
            __syncthreads();
            const short* Bs = diag ? At : Bt;
            #pragma unroll
            for (int sub = 0; sub < 2; ++sub) {
                int ko = sub * 32 + kg * 8;
                short8 a8[2];
                #pragma unroll
                for (int mt = 0; mt < 2; ++mt)
                    a8[mt] = *(const short8*)&At[((wave * 2 + mt) * 16 + m) * 72 + ko];
                #pragma unroll
                for (int ot = 0; ot < 8; ++ot) {
                    short8 b8 = *(const short8*)&Bs[(ot * 16 + m) * 72 + ko];
                    #pragma unroll
                    for (int mt = 0; mt < 2; ++mt)
                        acc[mt][ot] = __builtin_amdgcn_mfma_f32_16x16x32_bf16(a8[mt], b8, acc[mt][ot], 0, 0, 0);
                }
            }
            __syncthreads();
        }
        float* pd = cf.part + (((size_t)(n * cf.nch + ch) * cf.nt + ti) * cf.nt + tj) * 16384;
        #pragma unroll
        for (int mt = 0; mt < 2; ++mt)
            #pragma unroll
            for (int ot = 0; ot < 8; ++ot)
                #pragma unroll
                for (int r = 0; r < 4; ++r) {
                    int row = (wave * 2 + mt) * 16 + kg * 4 + r;
                    int col = ot * 16 + m;
                    pd[(size_t)row * 128 + col] = acc[mt][ot][r];
                }
    }
}

// ------------------------------------------------------------------ reduce ---
// Sum partial chunks into chunk-0 slot (levels with nch>1), massively parallel.
struct RedLvl { float* part; int nch; int shift; int base; };
struct RedParams { RedLvl r[3]; };

__global__ __launch_bounds__(256) void reduce_kernel(RedParams p) {
    int bid = blockIdx.x;
    int li = 0;
    #pragma unroll
    for (int i = 1; i < 3; ++i) if (bid >= p.r[i].base) li = i;
    RedLvl c = p.r[li];
    int rel = bid - c.base;
    int idx = rel * 256 + (int)threadIdx.x;
    int n   = idx >> c.shift;
    int i4  = idx & ((1 << c.shift) - 1);
    floatx4* p4 = (floatx4*)c.part;
    size_t b = ((size_t)n * c.nch) << c.shift;
    floatx4 s0 = {0,0,0,0}, s1 = {0,0,0,0}, s2 = {0,0,0,0}, s3 = {0,0,0,0};
    int ch = 0;
    for (; ch + 4 <= c.nch; ch += 4) {
        s0 += p4[b + ((size_t)ch       << c.shift) + i4];
        s1 += p4[b + ((size_t)(ch + 1) << c.shift) + i4];
        s2 += p4[b + ((size_t)(ch + 2) << c.shift) + i4];
        s3 += p4[b + ((size_t)(ch + 3) << c.shift) + i4];
    }
    for (; ch < c.nch; ++ch) s0 += p4[b + ((size_t)ch << c.shift) + i4];
    p4[b + i4] = (s0 + s1) + (s2 + s3);
}

// ------------------------------------------------------------------ qform ----
// T = G @ smT (G from reduced chunk-0, split hi/lo bf16); quad[o] += sm.T
__global__ __launch_bounds__(256) void qform_kernel(GramParams p, float* quad) {
    __shared__ __align__(16) short Ahi[128 * 40];
    __shared__ __align__(16) short Alo[128 * 40];
    __shared__ __align__(16) short Bs [128 * 40];

    int bid = blockIdx.x;
    int lvl = 0;
    #pragma unroll
    for (int i = 1; i < NLVL; ++i) if (bid >= p.l[i].qformBase) lvl = i;
    LvlCfg cf = p.l[lvl];
    int rel = bid - cf.qformBase;
    int n  = rel / cf.nt;
    int mb = rel - n * cf.nt;
    int R = cf.R;

    int t = threadIdx.x, wave = t >> 6, lane = t & 63;
    int m = lane & 15, kg = lane >> 4;
    int aIt    = R >> 5;
    int mtCnt  = R >> 6;
    int mtBase = wave * mtCnt;

    floatx4 acc[2][8];
    #pragma unroll
    for (int i = 0; i < 2; ++i)
        #pragma unroll
        for (int j = 0; j < 8; ++j) acc[i][j] = (floatx4){0.f, 0.f, 0.f, 0.f};

    size_t tileElems = (size_t)R * R;

    for (int ks = 0; ks < cf.C; ks += 32) {
        int tjk = ks >> 7;
        int kin = ks & 127;
        // ---- A staging: read reduced G tile (chunk 0), split hi/lo bf16
        #pragma unroll
        for (int i = 0; i < 4; ++i) if (i < aIt) {
            int row = (t >> 3) + 32 * i;
            int k4  = (t & 7) * 4;
            const float* src = cf.part
                + (((size_t)n * cf.nch * cf.nt + mb) * cf.nt + tjk) * tileElems
                + (size_t)row * R + kin + k4;
            floatx4 s = *(const floatx4*)src;
            uint32_t h0 = pk2bf(s.x, s.y), h1 = pk2bf(s.z, s.w);
            floatx4 resid;
            resid.x = s.x - bf_lo(h0); resid.y = s.y - bf_hi(h0);
            resid.z = s.z - bf_lo(h1); resid.w = s.w - bf_hi(h1);
            uint2 uh; uh.x = h0; uh.y = h1;
            uint2 ul; ul.x = pk2bf(resid.x, resid.y); ul.y = pk2bf(resid.z, resid.w);
            *(uint2*)&Ahi[row * 40 + k4] = uh;
            *(uint2*)&Alo[row * 40 + k4] = ul;
        }
        // ---- B staging: smT[o][ks..ks+32): 128 rows x 4 uint4 = 512 slots
        #pragma unroll
        for (int it = 0; it < 2; ++it) {
            int idx  = it * 256 + t;
            int o    = idx >> 2;
            int part = idx & 3;
            uint4 v = *(const uint4*)(cf.smT + (size_t)o * cf.C + ks + part * 8);
            *(uint4*)&Bs[o * 40 + part * 8] = v;
        }
        __syncthreads();

        short8 ah[2], al[2];
        #pragma unroll
        for (int mt = 0; mt < 2; ++mt) if (mt < mtCnt) {
            ah[mt] = *(const short8*)&Ahi[((mtBase + mt) * 16 + m) * 40 + kg * 8];
            al[mt] = *(const short8*)&Alo[((mtBase + mt) * 16 + m) * 40 + kg * 8];
        }
        #pragma unroll
        for (int ot = 0; ot < 8; ++ot) {
            short8 b8 = *(const short8*)&Bs[(ot * 16 + m) * 40 + kg * 8];
            #pragma unroll
            for (int mt = 0; mt < 2; ++mt) if (mt < mtCnt) {
                acc[mt][ot] = __builtin_amdgcn_mfma_f32_16x16x32_bf16(ah[mt], b8, acc[mt][ot], 0, 0, 0);
                acc[mt][ot] = __builtin_amdgcn_mfma_f32_16x16x32_bf16(al[mt], b8, acc[mt][ot], 0, 0, 0);
            }
        }
        __syncthreads();
    }

    // ---- epilogue: quad[o] += sum_c sm[c,o] * T[c,o]
    const float* smN = cf.smN;
    float* qb = quad + (size_t)(lvl * 8 + n) * NQ;
    #pragma unroll
    for (int ot = 0; ot < 8; ++ot) {
        float s = 0.f;
        #pragma unroll
        for (int mt = 0; mt < 2; ++mt) if (mt < mtCnt)
            #pragma unroll
            for (int r = 0; r < 4; ++r) {
                int c = mb * 128 + (mtBase + mt) * 16 + kg * 4 + r;
                int o = ot * 16 + m;
                s = fmaf(acc[mt][ot][r], smN[(size_t)c * NQ + o], s);
            }
        s += __shfl_xor(s, 16);
        s += __shfl_xor(s, 32);
        if (lane < 16) atomicAdd(qb + ot * 16 + lane, s);
    }
}

// ------------------------------------------------------------------- head ----
__device__ __forceinline__ float block_sum512(float v, float* red8, int t) {
    #pragma unroll
    for (int s = 32; s; s >>= 1) v += __shfl_xor(v, s);
    __syncthreads();
    if ((t & 63) == 0) red8[t >> 6] = v;
    __syncthreads();
    float tot = 0.f;
    #pragma unroll
    for (int i = 0; i < 8; ++i) tot += red8[i];
    return tot;
}

__global__ __launch_bounds__(512) void head_kernel(
    const float* __restrict__ quad,
    const float* __restrict__ wt1, const float* __restrict__ fc1_b,
    const float* __restrict__ wt2, const float* __restrict__ fc2_b,
    const float* __restrict__ wt3, const float* __restrict__ fc3_b,
    float* __restrict__ out) {
    __shared__ float feat[640];
    __shared__ float hbuf[512];
    __shared__ float red8[8];
    __shared__ float stats[10];
    int n = blockIdx.x;
    int t = threadIdx.x;

    for (int idx = t; idx < 640; idx += 512) {
        int lvl = idx >> 7, o = idx & 127;
        feat[idx] = quad[(size_t)(lvl * 8 + n) * NQ + o];
    }
    __syncthreads();
    if (t < 5) {
        float s = 0.f;
        for (int i = 0; i < 128; ++i) s += feat[t * 128 + i];
        float mean = s * (1.f / 128.f);
        float v = 0.f;
        for (int i = 0; i < 128; ++i) { float d = feat[t * 128 + i] - mean; v += d * d; }
        stats[t]     = mean;
        stats[5 + t] = sqrtf(v * (1.f / 127.f)) + 1e-8f;
    }
    __syncthreads();
    for (int idx = t; idx < 640; idx += 512) {
        int lvl = idx >> 7;
        feat[idx] = (feat[idx] - stats[lvl]) / stats[5 + lvl];
    }
    __syncthreads();

    float acc = fc1_b[t];
    {
        const float* wr = wt1 + (size_t)t * 640;
        #pragma unroll 4
        for (int k = 0; k < 640; k += 4) {
            floatx4 wv = *(const floatx4*)(wr + k);
            floatx4 fv = *(const floatx4*)&feat[k];
            acc = fmaf(wv.x, fv.x, acc); acc = fmaf(wv.y, fv.y, acc);
            acc = fmaf(wv.z, fv.z, acc); acc = fmaf(wv.w, fv.w, acc);
        }
    }
    float mean = block_sum512(acc, red8, t) * (1.f / 512.f);
    float d    = acc - mean;
    float var  = block_sum512(d * d, red8, t) * (1.f / 511.f);
    float nv   = d / (sqrtf(var) + 1e-8f);
    __syncthreads();
    hbuf[t] = nv > 0.f ? nv : 0.01f * nv;
    __syncthreads();

    float acc2 = fc2_b[t];
    {
        const float* wr = wt2 + (size_t)t * 512;
        #pragma unroll 4
        for (int k = 0; k < 512; k += 4) {
            floatx4 wv = *(const floatx4*)(wr + k);
            floatx4 fv = *(const floatx4*)&hbuf[k];
            acc2 = fmaf(wv.x, fv.x, acc2); acc2 = fmaf(wv.y, fv.y, acc2);
            acc2 = fmaf(wv.z, fv.z, acc2); acc2 = fmaf(wv.w, fv.w, acc2);
        }
    }
    mean = block_sum512(acc2, red8, t) * (1.f / 512.f);
    d    = acc2 - mean;
    var  = block_sum512(d * d, red8, t) * (1.f / 511.f);
    nv   = d / (sqrtf(var) + 1e-8f);
    __syncthreads();
    hbuf[t] = nv > 0.f ? nv : 0.01f * nv;
    __syncthreads();

    if (t < 128) {
        float acc3 = fc3_b[t];
        const float* wr = wt3 + (size_t)t * 512;
        #pragma unroll 4
        for (int k = 0; k < 512; k += 4) {
            floatx4 wv = *(const floatx4*)(wr + k);
            floatx4 fv = *(const floatx4*)&hbuf[k];
            acc3 = fmaf(wv.x, fv.x, acc3); acc3 = fmaf(wv.y, fv.y, acc3);
            acc3 = fmaf(wv.z, fv.z, acc3); acc3 = fmaf(wv.w, fv.w, acc3);
        }
        out[(size_t)n * NQ + t] = acc3;
    }
}

// ----------------------------------------------------------------- launch ----
extern "C" void kernel_launch(void* const* d_in, const int* in_sizes, int n_in,
                              void* d_out, int out_size, void* d_ws, size_t ws_size,
                              hipStream_t stream) {
    static const int Cs  [NLVL] = {64, 128, 256, 512, 512};
    static const int HWs [NLVL] = {65536, 16384, 4096, 1024, 256};
    static const int NTs [NLVL] = {1, 1, 2, 4, 4};
    static const int Rs  [NLVL] = {64, 128, 128, 128, 128};
    static const int NCHs[NLVL] = {64, 16, 4, 1, 1};
    // launch order: big blocks first, sea of small lvl0 blocks last
    static const int ORDER[NLVL] = {2, 3, 1, 4, 0};

    const float* x[NLVL];
    const float* w[NLVL];
    for (int i = 0; i < NLVL; ++i) {
        x[i] = (const float*)d_in[2 * i];
        w[i] = (const float*)d_in[2 * i + 1];
    }
    const float* fc1_w = (const float*)d_in[10];
    const float* fc1_b = (const float*)d_in[11];
    const float* fc2_w = (const float*)d_in[12];
    const float* fc2_b = (const float*)d_in[13];
    const float* fc3_w = (const float*)d_in[14];
    const float* fc3_b = (const float*)d_in[15];

    // ---- workspace layout (~40.1 MB)
    char* ws = (char*)d_ws;
    size_t off = 0;
    float* part[NLVL];
    for (int l = 0; l < NLVL; ++l) {
        part[l] = (float*)(ws + off);
        off += (size_t)8 * NCHs[l] * NTs[l] * NTs[l] * Rs[l] * Rs[l] * sizeof(float);
    }
    uint16_t* smT[NLVL];
    for (int l = 0; l < NLVL; ++l) { smT[l] = (uint16_t*)(ws + off); off += (size_t)Cs[l] * NQ * sizeof(uint16_t); }
    off = (off + 15) & ~(size_t)15;
    float* smN[NLVL];
    for (int l = 0; l < NLVL; ++l) { smN[l] = (float*)(ws + off); off += (size_t)Cs[l] * NQ * sizeof(float); }
    float* wt1 = (float*)(ws + off); off += (size_t)512 * 640 * sizeof(float);
    float* wt2 = (float*)(ws + off); off += (size_t)512 * 512 * sizeof(float);
    float* wt3 = (float*)(ws + off); off += (size_t)128 * 512 * sizeof(float);
    float* quad = (float*)(ws + off); off += (size_t)NLVL * 8 * NQ * sizeof(float);
    (void)ws_size;

    // ---- params
    SmParams sp;
    for (int l = 0; l < NLVL; ++l) { sp.w[l] = w[l]; sp.smT[l] = smT[l]; sp.smN[l] = smN[l]; sp.C[l] = Cs[l]; }

    GramParams gp;
    int qBase = 0;
    for (int l = 0; l < NLVL; ++l) {
        LvlCfg& c = gp.l[l];
        c.x = x[l]; c.part = part[l]; c.smT = smT[l]; c.smN = smN[l];
        c.C = Cs[l]; c.HW = HWs[l]; c.nt = NTs[l]; c.R = Rs[l];
        c.nch = NCHs[l]; c.chunkH = HWs[l] / NCHs[l];
        c.ksteps = c.chunkH / (l == 0 ? 128 : 64);
        c.gramCnt = 8 * c.nch * c.nt * c.nt;
        c.qformBase = qBase; qBase += 8 * c.nt;
    }
    int gBase = 0;
    for (int i = 0; i < NLVL; ++i) {
        LvlCfg& c = gp.l[ORDER[i]];
        c.gramBase = gBase;
        gBase += c.gramCnt;       // total 1024
    }

    RedParams rp;
    rp.r[0] = {part[0], NCHs[0], 10, 0};     // 8*4096/4/256  = 32 blocks
    rp.r[1] = {part[1], NCHs[1], 12, 32};    // 8*16384/4/256 = 128 blocks
    rp.r[2] = {part[2], NCHs[2], 14, 160};   // 8*65536/4/256 = 512 blocks
    int rBlocks = 672;

    TrParams tp;
    tp.m[0] = {fc1_w, wt1, 640, 512, 0};
    tp.m[1] = {fc2_w, wt2, 512, 512, 320};
    tp.m[2] = {fc3_w, wt3, 512, 128, 576};

    // ---- launches
    softmax_kernel<<<NLVL * NQ, 64, 0, stream>>>(sp);
    wtrans_kernel<<<640, 256, 0, stream>>>(tp);
    hipMemsetAsync(quad, 0, (size_t)NLVL * 8 * NQ * sizeof(float), stream);
    gram_kernel<<<gBase, 256, 0, stream>>>(gp);            // 1024 blocks
    reduce_kernel<<<rBlocks, 256, 0, stream>>>(rp);
    qform_kernel<<<qBase, 256, 0, stream>>>(gp, quad);     // 96 blocks
    head_kernel<<<8, 512, 0, stream>>>(quad, wt1, fc1_b, wt2, fc2_b, wt3, fc3_b,
                                       (float*)d_out);
}